// Round 2
// baseline (1619.943 us; speedup 1.0000x reference)
//
#include <hip/hip_runtime.h>

#define DMODEL 768
#define NHEADS 12

// C[M,768] = A[M,768] @ W[768,768]^T + bias  (A rows optionally gathered via row_map)
// All f32, f32 accumulate.
__global__ __launch_bounds__(256) void gemm768(const float* __restrict__ A,
                                               const float* __restrict__ W,
                                               const float* __restrict__ bias,
                                               const int* __restrict__ row_map,
                                               float* __restrict__ C, int M) {
  constexpr int K = DMODEL;
  __shared__ float As[16][132];   // k-major: As[kk][m]
  __shared__ float Ws[16][132];   // k-major: Ws[kk][n]
  const int t = threadIdx.x;
  const int bm = blockIdx.y * 128;
  const int bn = blockIdx.x * 128;
  const int tx = t & 15, ty = t >> 4;

  float acc[8][8];
#pragma unroll
  for (int i = 0; i < 8; ++i)
#pragma unroll
    for (int j = 0; j < 8; ++j) acc[i][j] = 0.f;

  // staging: each thread loads 8 consecutive k-elements of one row (32B)
  const int lr = t >> 1;          // 0..127 tile row
  const int lc = (t & 1) * 8;     // 0 or 8 within BK=16
  const int am = bm + lr;
  const bool amok = am < M;
  const int arow = amok ? (row_map ? row_map[am] : am) : 0;
  const int wrow = bn + lr;       // < 768 always

  for (int k0 = 0; k0 < K; k0 += 16) {
    float av[8], wv[8];
    if (amok) {
      const float* src = A + (size_t)arow * K + k0 + lc;
      float4 f0 = *(const float4*)(src);
      float4 f1 = *(const float4*)(src + 4);
      av[0]=f0.x; av[1]=f0.y; av[2]=f0.z; av[3]=f0.w;
      av[4]=f1.x; av[5]=f1.y; av[6]=f1.z; av[7]=f1.w;
    } else {
#pragma unroll
      for (int j = 0; j < 8; ++j) av[j] = 0.f;
    }
    {
      const float* src = W + (size_t)wrow * K + k0 + lc;
      float4 f0 = *(const float4*)(src);
      float4 f1 = *(const float4*)(src + 4);
      wv[0]=f0.x; wv[1]=f0.y; wv[2]=f0.z; wv[3]=f0.w;
      wv[4]=f1.x; wv[5]=f1.y; wv[6]=f1.z; wv[7]=f1.w;
    }
#pragma unroll
    for (int j = 0; j < 8; ++j) {
      As[lc + j][lr] = av[j];
      Ws[lc + j][lr] = wv[j];
    }
    __syncthreads();
#pragma unroll
    for (int kk = 0; kk < 16; ++kk) {
      float a[8], w[8];
      *(float4*)&a[0] = *(const float4*)&As[kk][ty * 8];
      *(float4*)&a[4] = *(const float4*)&As[kk][ty * 8 + 4];
      *(float4*)&w[0] = *(const float4*)&Ws[kk][tx * 8];
      *(float4*)&w[4] = *(const float4*)&Ws[kk][tx * 8 + 4];
#pragma unroll
      for (int i = 0; i < 8; ++i)
#pragma unroll
        for (int j = 0; j < 8; ++j) acc[i][j] += a[i] * w[j];
    }
    __syncthreads();
  }

  const int col = bn + tx * 8;
  float4 b0 = *(const float4*)(bias + col);
  float4 b1 = *(const float4*)(bias + col + 4);

#pragma unroll
  for (int i = 0; i < 8; ++i) {
    int row = bm + ty * 8 + i;
    if (row >= M) continue;
    float* Cf = C + (size_t)row * K + col;
    *(float4*)(Cf)     = make_float4(acc[i][0]+b0.x, acc[i][1]+b0.y,
                                     acc[i][2]+b0.z, acc[i][3]+b0.w);
    *(float4*)(Cf + 4) = make_float4(acc[i][4]+b1.x, acc[i][5]+b1.y,
                                     acc[i][6]+b1.z, acc[i][7]+b1.w);
  }
}

// one block: prefix-scan query_mask -> left/right per feature + valid-key counts
__global__ __launch_bounds__(1024) void build_segments(const int* __restrict__ qm,
    const int* __restrict__ ids, const int* __restrict__ padp,
    int n, int f, int* __restrict__ left, int* __restrict__ right,
    int* __restrict__ nvalid) {
  __shared__ int cnt[1024];
  const int t = threadIdx.x;
  const int per = (n + 1023) >> 10;
  const int base = t * per;
  int c = 0;
  for (int i = 0; i < per; ++i) {
    int p = base + i;
    if (p < n && qm[p] != 0) ++c;
  }
  cnt[t] = c;
  __syncthreads();
  for (int off = 1; off < 1024; off <<= 1) {
    int v = (t >= off) ? cnt[t - off] : 0;
    __syncthreads();
    cnt[t] += v;
    __syncthreads();
  }
  int r = cnt[t] - c;  // exclusive prefix
  for (int i = 0; i < per; ++i) {
    int p = base + i;
    if (p < n && qm[p] != 0) {
      if (r < f) left[r] = p;
      ++r;
    }
  }
  __syncthreads();
  const int pad = *padp;
  for (int i = t; i < f; i += 1024) {
    int L0 = left[i];
    int R0 = (i + 1 < f) ? left[i + 1] : n;
    right[i] = R0;
    int cv = 0;
    for (int p = L0; p < R0; ++p) cv += (ids[p] != pad) ? 1 : 0;
    nvalid[i] = cv;
  }
}

__device__ __forceinline__ float allreduce64(float x) {
#pragma unroll
  for (int m = 1; m < 64; m <<= 1) x += __shfl_xor(x, m, 64);
  return x;
}

// normal features: online softmax over the (short) segment, skipping pad keys.
// lane = head dim. Out-of-segment / pad contributions underflow to exact 0 in the
// reference's f32 softmax (exp(raw/8 - 10000 - max) == 0), so segment-only is exact.
__global__ __launch_bounds__(64) void attn_seg(const float* __restrict__ q,
    const float* __restrict__ k, const float* __restrict__ v,
    const int* __restrict__ left, const int* __restrict__ right,
    const int* __restrict__ nvalid, const int* __restrict__ ids,
    const int* __restrict__ padp, float* __restrict__ out) {
  const int feat = blockIdx.x, h = blockIdx.y, lane = threadIdx.x;
  if (nvalid[feat] == 0) return;  // handled by attn_full
  const int off = h * 64 + lane;
  const int pad = *padp;
  const float qv = q[(size_t)feat * DMODEL + off];
  float m = -1e30f, l = 0.f, acc = 0.f;
  const int L0 = left[feat], R0 = right[feat];
  for (int p = L0; p < R0; ++p) {
    if (ids[p] == pad) continue;
    float s = allreduce64(qv * k[(size_t)p * DMODEL + off]) * 0.125f;
    float mn = fmaxf(m, s);
    float al = __expf(m - mn);
    float w = __expf(s - mn);
    l = l * al + w;
    acc = acc * al + w * v[(size_t)p * DMODEL + off];
    m = mn;
  }
  out[(size_t)feat * DMODEL + off] = acc / l;
}

// fully-masked features: uniform -10000 bias cancels in softmax -> full softmax
// over ALL n keys (pads included, cross-batch). 8 waves split the keys.
__global__ __launch_bounds__(512) void attn_full(const float* __restrict__ q,
    const float* __restrict__ k, const float* __restrict__ v,
    const int* __restrict__ nvalid, int n, float* __restrict__ out) {
  const int feat = blockIdx.x, h = blockIdx.y;
  if (nvalid[feat] != 0) return;
  const int t = threadIdx.x, wave = t >> 6, lane = t & 63;
  const int off = h * 64 + lane;
  const float qv = q[(size_t)feat * DMODEL + off];
  float m = -1e30f, l = 0.f, acc = 0.f;
  for (int p = wave; p < n; p += 8) {
    float s = allreduce64(qv * k[(size_t)p * DMODEL + off]) * 0.125f;
    float mn = fmaxf(m, s);
    float al = __expf(m - mn);
    float w = __expf(s - mn);
    l = l * al + w;
    acc = acc * al + w * v[(size_t)p * DMODEL + off];
    m = mn;
  }
  __shared__ float sm[8], sl[8], sa[8][64];
  if (lane == 0) { sm[wave] = m; sl[wave] = l; }
  sa[wave][lane] = acc;
  __syncthreads();
  if (wave == 0) {
    float M = -1e30f;
#pragma unroll
    for (int w2 = 0; w2 < 8; ++w2) M = fmaxf(M, sm[w2]);
    float Lt = 0.f, At = 0.f;
#pragma unroll
    for (int w2 = 0; w2 < 8; ++w2) {
      float sc = __expf(sm[w2] - M);
      Lt += sl[w2] * sc;
      At += sa[w2][lane] * sc;
    }
    out[(size_t)feat * DMODEL + off] = At / Lt;
  }
}

extern "C" void kernel_launch(void* const* d_in, const int* in_sizes, int n_in,
                              void* d_out, int out_size, void* d_ws, size_t ws_size,
                              hipStream_t stream) {
  const float* x_qk = (const float*)d_in[0];
  const float* x_v  = (const float*)d_in[1];
  const int* qm     = (const int*)d_in[2];
  const int* ids    = (const int*)d_in[3];
  const int* padp   = (const int*)d_in[4];
  const float* Wq = (const float*)d_in[5];
  const float* bq = (const float*)d_in[6];
  const float* Wk = (const float*)d_in[7];
  const float* bk = (const float*)d_in[8];
  const float* Wv = (const float*)d_in[9];
  const float* bv = (const float*)d_in[10];
  const float* Wo = (const float*)d_in[11];
  const float* bo = (const float*)d_in[12];

  const int n = in_sizes[0] / DMODEL;   // 8192
  const int f = out_size / DMODEL;      // 1024

  // workspace layout (f32): k[n,768] v[n,768] q[f,768] attn[f,768] + int arrays
  float* kf = (float*)d_ws;
  float* vf = kf + (size_t)n * DMODEL;
  float* qf = vf + (size_t)n * DMODEL;
  float* af = qf + (size_t)f * DMODEL;
  int* left   = (int*)(af + (size_t)f * DMODEL);
  int* right  = left + f;
  int* nvalid = right + f;

  build_segments<<<1, 1024, 0, stream>>>(qm, ids, padp, n, f, left, right, nvalid);

  dim3 gKV(6, (n + 127) / 128);
  dim3 gF(6, (f + 127) / 128);
  gemm768<<<gKV, 256, 0, stream>>>(x_qk, Wk, bk, nullptr, kf, n);
  gemm768<<<gKV, 256, 0, stream>>>(x_v,  Wv, bv, nullptr, vf, n);
  gemm768<<<gF,  256, 0, stream>>>(x_qk, Wq, bq, left,    qf, f);

  attn_seg <<<dim3(f, NHEADS),  64, 0, stream>>>(qf, kf, vf, left, right, nvalid, ids, padp, af);
  attn_full<<<dim3(f, NHEADS), 512, 0, stream>>>(qf, kf, vf, nvalid, n, af);

  gemm768<<<gF, 256, 0, stream>>>(af, Wo, bo, nullptr, (float*)d_out, f);
}

// Round 3
// 704.522 us; speedup vs baseline: 2.2993x; 2.2993x over previous
//
#include <hip/hip_runtime.h>

#define DMODEL 768
#define NHEADS 12
#define MAXFULL 32

// C[M,768] = A[M,768] @ W[768,768]^T + bias  (A rows optionally gathered via row_map)
// All f32, f32 accumulate.
__global__ __launch_bounds__(256) void gemm768(const float* __restrict__ A,
                                               const float* __restrict__ W,
                                               const float* __restrict__ bias,
                                               const int* __restrict__ row_map,
                                               float* __restrict__ C, int M) {
  constexpr int K = DMODEL;
  __shared__ float As[16][132];   // k-major: As[kk][m]
  __shared__ float Ws[16][132];   // k-major: Ws[kk][n]
  const int t = threadIdx.x;
  const int bm = blockIdx.y * 128;
  const int bn = blockIdx.x * 128;
  const int tx = t & 15, ty = t >> 4;

  float acc[8][8];
#pragma unroll
  for (int i = 0; i < 8; ++i)
#pragma unroll
    for (int j = 0; j < 8; ++j) acc[i][j] = 0.f;

  const int lr = t >> 1;          // 0..127 tile row
  const int lc = (t & 1) * 8;     // 0 or 8 within BK=16
  const int am = bm + lr;
  const bool amok = am < M;
  const int arow = amok ? (row_map ? row_map[am] : am) : 0;
  const int wrow = bn + lr;       // < 768 always

  for (int k0 = 0; k0 < K; k0 += 16) {
    float av[8], wv[8];
    if (amok) {
      const float* src = A + (size_t)arow * K + k0 + lc;
      float4 f0 = *(const float4*)(src);
      float4 f1 = *(const float4*)(src + 4);
      av[0]=f0.x; av[1]=f0.y; av[2]=f0.z; av[3]=f0.w;
      av[4]=f1.x; av[5]=f1.y; av[6]=f1.z; av[7]=f1.w;
    } else {
#pragma unroll
      for (int j = 0; j < 8; ++j) av[j] = 0.f;
    }
    {
      const float* src = W + (size_t)wrow * K + k0 + lc;
      float4 f0 = *(const float4*)(src);
      float4 f1 = *(const float4*)(src + 4);
      wv[0]=f0.x; wv[1]=f0.y; wv[2]=f0.z; wv[3]=f0.w;
      wv[4]=f1.x; wv[5]=f1.y; wv[6]=f1.z; wv[7]=f1.w;
    }
#pragma unroll
    for (int j = 0; j < 8; ++j) {
      As[lc + j][lr] = av[j];
      Ws[lc + j][lr] = wv[j];
    }
    __syncthreads();
#pragma unroll
    for (int kk = 0; kk < 16; ++kk) {
      float a[8], w[8];
      *(float4*)&a[0] = *(const float4*)&As[kk][ty * 8];
      *(float4*)&a[4] = *(const float4*)&As[kk][ty * 8 + 4];
      *(float4*)&w[0] = *(const float4*)&Ws[kk][tx * 8];
      *(float4*)&w[4] = *(const float4*)&Ws[kk][tx * 8 + 4];
#pragma unroll
      for (int i = 0; i < 8; ++i)
#pragma unroll
        for (int j = 0; j < 8; ++j) acc[i][j] += a[i] * w[j];
    }
    __syncthreads();
  }

  const int col = bn + tx * 8;
  float4 b0 = *(const float4*)(bias + col);
  float4 b1 = *(const float4*)(bias + col + 4);

#pragma unroll
  for (int i = 0; i < 8; ++i) {
    int row = bm + ty * 8 + i;
    if (row >= M) continue;
    float* Cf = C + (size_t)row * K + col;
    *(float4*)(Cf)     = make_float4(acc[i][0]+b0.x, acc[i][1]+b0.y,
                                     acc[i][2]+b0.z, acc[i][3]+b0.w);
    *(float4*)(Cf + 4) = make_float4(acc[i][4]+b1.x, acc[i][5]+b1.y,
                                     acc[i][6]+b1.z, acc[i][7]+b1.w);
  }
}

// one block: prefix-scan query_mask -> left/right/nvalid per feature,
// plus compact list of fully-masked features (nvalid==0).
__global__ __launch_bounds__(1024) void build_segments(const int* __restrict__ qm,
    const int* __restrict__ ids, const int* __restrict__ padp,
    int n, int f, int* __restrict__ left, int* __restrict__ right,
    int* __restrict__ nvalid, int* __restrict__ fullrank,
    int* __restrict__ fullist, int* __restrict__ nfull) {
  __shared__ int cnt[1024];
  __shared__ int fullcnt;
  const int t = threadIdx.x;
  if (t == 0) fullcnt = 0;
  const int per = (n + 1023) >> 10;
  const int base = t * per;
  int c = 0;
  for (int i = 0; i < per; ++i) {
    int p = base + i;
    if (p < n && qm[p] != 0) ++c;
  }
  cnt[t] = c;
  __syncthreads();
  for (int off = 1; off < 1024; off <<= 1) {
    int v = (t >= off) ? cnt[t - off] : 0;
    __syncthreads();
    cnt[t] += v;
    __syncthreads();
  }
  int r = cnt[t] - c;  // exclusive prefix
  for (int i = 0; i < per; ++i) {
    int p = base + i;
    if (p < n && qm[p] != 0) {
      if (r < f) left[r] = p;
      ++r;
    }
  }
  __syncthreads();
  const int pad = *padp;
  for (int i = t; i < f; i += 1024) {
    int L0 = left[i];
    int R0 = (i + 1 < f) ? left[i + 1] : n;
    right[i] = R0;
    int cv = 0;
    for (int p = L0; p < R0; ++p) cv += (ids[p] != pad) ? 1 : 0;
    nvalid[i] = cv;
    if (cv == 0) {
      int rk = atomicAdd(&fullcnt, 1);
      if (rk < MAXFULL) { fullist[rk] = i; fullrank[i] = rk; }
      else fullrank[i] = -1;
    } else {
      fullrank[i] = -1;
    }
  }
  __syncthreads();
  if (t == 0) *nfull = (fullcnt < MAXFULL) ? fullcnt : MAXFULL;
}

__device__ __forceinline__ float allreduce64(float x) {
#pragma unroll
  for (int m = 1; m < 64; m <<= 1) x += __shfl_xor(x, m, 64);
  return x;
}

// normal features: online softmax over the (short) segment, skipping pad keys.
// Out-of-segment / pad contributions underflow to exact 0 in the reference's
// f32 softmax (exp(raw/8 - 10000 - max) == 0), so segment-only is exact.
__global__ __launch_bounds__(64) void attn_seg(const float* __restrict__ q,
    const float* __restrict__ k, const float* __restrict__ v,
    const int* __restrict__ left, const int* __restrict__ right,
    const int* __restrict__ nvalid, const int* __restrict__ ids,
    const int* __restrict__ padp, float* __restrict__ out) {
  const int feat = blockIdx.x, h = blockIdx.y, lane = threadIdx.x;
  if (nvalid[feat] == 0) return;  // handled by attn_full_*
  const int off = h * 64 + lane;
  const int pad = *padp;
  const float qv = q[(size_t)feat * DMODEL + off];
  float m = -1e30f, l = 0.f, acc = 0.f;
  const int L0 = left[feat], R0 = right[feat];
  for (int p = L0; p < R0; ++p) {
    if (ids[p] == pad) continue;
    float s = allreduce64(qv * k[(size_t)p * DMODEL + off]) * 0.125f;
    float mn = fmaxf(m, s);
    float al = __expf(m - mn);
    float w = __expf(s - mn);
    l = l * al + w;
    acc = acc * al + w * v[(size_t)p * DMODEL + off];
    m = mn;
  }
  out[(size_t)feat * DMODEL + off] = acc / l;
}

// fully-masked features: uniform -10000 bias cancels in softmax -> full softmax
// over ALL n keys (pads included, cross-batch). Split-K pass 1: each work item
// = (full-feature, head, key-split) -> partial (m, l, acc[64]).
__global__ __launch_bounds__(512) void attn_full_part(const float* __restrict__ q,
    const float* __restrict__ k, const float* __restrict__ v,
    const int* __restrict__ fullist, const int* __restrict__ nfullp,
    int n, int split, float* __restrict__ pm, float* __restrict__ pl,
    float* __restrict__ pacc) {
  const int nfull = *nfullp;
  const int nitems = nfull * NHEADS * split;
  const int t = threadIdx.x, wave = t >> 6, lane = t & 63;
  __shared__ float sm[8], sl[8], sa[8][64];
  const int keys = n / split;
  for (int item = blockIdx.x; item < nitems; item += gridDim.x) {
    const int fl = item / (NHEADS * split);
    const int rem = item % (NHEADS * split);
    const int h = rem / split;
    const int sp = rem % split;
    const int feat = fullist[fl];
    const int off = h * 64 + lane;
    const float qv = q[(size_t)feat * DMODEL + off];
    const int p0 = sp * keys;
    float m = -1e30f, l = 0.f, acc = 0.f;
    for (int p = p0 + wave; p < p0 + keys; p += 8) {
      float s = allreduce64(qv * k[(size_t)p * DMODEL + off]) * 0.125f;
      float mn = fmaxf(m, s);
      float al = __expf(m - mn);
      float w = __expf(s - mn);
      l = l * al + w;
      acc = acc * al + w * v[(size_t)p * DMODEL + off];
      m = mn;
    }
    if (lane == 0) { sm[wave] = m; sl[wave] = l; }
    sa[wave][lane] = acc;
    __syncthreads();
    if (wave == 0) {
      float M = -1e30f;
#pragma unroll
      for (int w2 = 0; w2 < 8; ++w2) M = fmaxf(M, sm[w2]);
      float Lt = 0.f, At = 0.f;
#pragma unroll
      for (int w2 = 0; w2 < 8; ++w2) {
        float sc = __expf(sm[w2] - M);
        Lt += sl[w2] * sc;
        At += sa[w2][lane] * sc;
      }
      size_t idx = ((size_t)fl * NHEADS + h) * split + sp;
      if (lane == 0) { pm[idx] = M; pl[idx] = Lt; }
      pacc[idx * 64 + lane] = At;
    }
    __syncthreads();
  }
}

// Split-K pass 2: merge the `split` partials per (feature, head).
__global__ __launch_bounds__(64) void attn_full_comb(
    const int* __restrict__ nvalid, const int* __restrict__ fullrank,
    int split, const float* __restrict__ pm, const float* __restrict__ pl,
    const float* __restrict__ pacc, float* __restrict__ out) {
  const int feat = blockIdx.x, h = blockIdx.y, lane = threadIdx.x;
  if (nvalid[feat] != 0) return;
  const int fl = fullrank[feat];
  if (fl < 0) return;
  const size_t base = ((size_t)fl * NHEADS + h) * split;
  float M = -1e30f;
  for (int sp = 0; sp < split; ++sp) M = fmaxf(M, pm[base + sp]);
  float Lt = 0.f, At = 0.f;
  for (int sp = 0; sp < split; ++sp) {
    float sc = __expf(pm[base + sp] - M);
    Lt += pl[base + sp] * sc;
    At += pacc[(base + sp) * 64 + lane] * sc;
  }
  out[(size_t)feat * DMODEL + h * 64 + lane] = At / Lt;
}

extern "C" void kernel_launch(void* const* d_in, const int* in_sizes, int n_in,
                              void* d_out, int out_size, void* d_ws, size_t ws_size,
                              hipStream_t stream) {
  const float* x_qk = (const float*)d_in[0];
  const float* x_v  = (const float*)d_in[1];
  const int* qm     = (const int*)d_in[2];
  const int* ids    = (const int*)d_in[3];
  const int* padp   = (const int*)d_in[4];
  const float* Wq = (const float*)d_in[5];
  const float* bq = (const float*)d_in[6];
  const float* Wk = (const float*)d_in[7];
  const float* bk = (const float*)d_in[8];
  const float* Wv = (const float*)d_in[9];
  const float* bv = (const float*)d_in[10];
  const float* Wo = (const float*)d_in[11];
  const float* bo = (const float*)d_in[12];

  const int n = in_sizes[0] / DMODEL;   // 8192
  const int f = out_size / DMODEL;      // 1024

  // workspace layout (f32): k[n,768] v[n,768] q[f,768] attn[f,768] | ints | partials
  float* kf = (float*)d_ws;
  float* vf = kf + (size_t)n * DMODEL;
  float* qf = vf + (size_t)n * DMODEL;
  float* af = qf + (size_t)f * DMODEL;
  int* left     = (int*)(af + (size_t)f * DMODEL);
  int* right    = left + f;
  int* nvalid   = right + f;
  int* fullrank = nvalid + f;
  int* fullist  = fullrank + f;
  int* nfull    = fullist + MAXFULL;
  // align partial storage to 256 B
  size_t off_bytes = ((size_t)((char*)(nfull + 1) - (char*)d_ws) + 255) & ~(size_t)255;
  // choose split count that fits remaining workspace (worst-case MAXFULL features)
  int split = 64;
  while (split > 8) {
    size_t need = (size_t)MAXFULL * NHEADS * split * 66 * sizeof(float);
    if (off_bytes + need <= ws_size) break;
    split >>= 1;
  }
  float* pm = (float*)((char*)d_ws + off_bytes);
  float* pl = pm + (size_t)MAXFULL * NHEADS * split;
  float* pacc = pl + (size_t)MAXFULL * NHEADS * split;

  build_segments<<<1, 1024, 0, stream>>>(qm, ids, padp, n, f, left, right,
                                         nvalid, fullrank, fullist, nfull);

  dim3 gKV(6, (n + 127) / 128);
  dim3 gF(6, (f + 127) / 128);
  gemm768<<<gKV, 256, 0, stream>>>(x_qk, Wk, bk, nullptr, kf, n);
  gemm768<<<gKV, 256, 0, stream>>>(x_v,  Wv, bv, nullptr, vf, n);
  gemm768<<<gF,  256, 0, stream>>>(x_qk, Wq, bq, left,    qf, f);

  attn_seg<<<dim3(f, NHEADS), 64, 0, stream>>>(qf, kf, vf, left, right, nvalid,
                                               ids, padp, af);
  attn_full_part<<<3072, 512, 0, stream>>>(qf, kf, vf, fullist, nfull, n, split,
                                           pm, pl, pacc);
  attn_full_comb<<<dim3(f, NHEADS), 64, 0, stream>>>(nvalid, fullrank, split,
                                                     pm, pl, pacc, af);

  gemm768<<<gF, 256, 0, stream>>>(af, Wo, bo, nullptr, (float*)d_out, f);
}

// Round 4
// 362.925 us; speedup vs baseline: 4.4636x; 1.9412x over previous
//
#include <hip/hip_runtime.h>

#define DMODEL 768
#define NHEADS 12
#define MAXFULL 16

typedef __attribute__((ext_vector_type(8))) short short8;
typedef __attribute__((ext_vector_type(4))) float f32x4;

__device__ __forceinline__ unsigned pack2_bf16(float a, float b) {
  unsigned ua = __float_as_uint(a), ub = __float_as_uint(b);
  ua = (ua + 0x7fffu + ((ua >> 16) & 1u)) >> 16;
  ub = (ub + 0x7fffu + ((ub >> 16) & 1u)) & 0xffff0000u;
  return ua | ub;
}
__device__ __forceinline__ unsigned short bf16_1(float a) {
  unsigned ua = __float_as_uint(a);
  return (unsigned short)((ua + 0x7fffu + ((ua >> 16) & 1u)) >> 16);
}

// convert the 4 weight matrices f32 -> bf16 once
__global__ __launch_bounds__(256) void convW(const float* __restrict__ w0,
    const float* __restrict__ w1, const float* __restrict__ w2,
    const float* __restrict__ w3, unsigned* __restrict__ o0,
    unsigned* __restrict__ o1, unsigned* __restrict__ o2,
    unsigned* __restrict__ o3, int count) {  // count = elems per matrix
  const int nv = count >> 2;                 // float4s per matrix
  const float* src[4] = {w0, w1, w2, w3};
  unsigned* dst[4] = {o0, o1, o2, o3};
  for (int idx = blockIdx.x * 256 + threadIdx.x; idx < 4 * nv;
       idx += gridDim.x * 256) {
    int m = idx / nv, r = idx - m * nv;
    float4 v = ((const float4*)src[m])[r];
    dst[m][2 * r]     = pack2_bf16(v.x, v.y);
    dst[m][2 * r + 1] = pack2_bf16(v.z, v.w);
  }
}

// C[M,768] = A[M,768] @ W^T + bias. W pre-converted bf16 [col][k].
// A is f32 (converted in-loop) or bf16. MFMA 16x16x32 bf16, f32 accumulate.
// 128x128 tile, BK=32, 4 waves x (4x4 16x16 frags).
template<int A_F32>
__global__ __launch_bounds__(256) void gemm_mfma(const void* __restrict__ Ap,
    const unsigned short* __restrict__ Wb, const float* __restrict__ bias,
    const int* __restrict__ row_map, float* __restrict__ C, int M) {
  __shared__ unsigned short As[128 * 40];  // row stride 40 (80B = 20 banks): 2-way = free
  __shared__ unsigned short Bs[128 * 40];
  const int t = threadIdx.x;
  const int bm = blockIdx.y * 128, bn = blockIdx.x * 128;
  const int lane = t & 63, wid = t >> 6;
  const int m16 = lane & 15, quad = lane >> 4;
  const int wm = (wid >> 1) * 64, wn = (wid & 1) * 64;

  f32x4 acc[4][4];
#pragma unroll
  for (int i = 0; i < 4; ++i)
#pragma unroll
    for (int j = 0; j < 4; ++j) acc[i][j] = (f32x4){0.f, 0.f, 0.f, 0.f};

  // staging: thread t loads 16 k-elements of one row of A and of W
  const int srow = t >> 1, skc = (t & 1) * 16;
  const int am = bm + srow;
  const bool amok = am < M;
  const int arow = amok ? (row_map ? row_map[am] : am) : 0;
  const int wrow = bn + srow;  // < 768 always
  const float* Af = (const float*)Ap;
  const unsigned short* Ab = (const unsigned short*)Ap;

  for (int k0 = 0; k0 < DMODEL; k0 += 32) {
    uint4 aw0, aw1;
    if (A_F32) {
      if (amok) {
        const float4* pa = (const float4*)(Af + (size_t)arow * DMODEL + k0 + skc);
        float4 f0 = pa[0], f1 = pa[1], f2 = pa[2], f3 = pa[3];
        aw0 = make_uint4(pack2_bf16(f0.x, f0.y), pack2_bf16(f0.z, f0.w),
                         pack2_bf16(f1.x, f1.y), pack2_bf16(f1.z, f1.w));
        aw1 = make_uint4(pack2_bf16(f2.x, f2.y), pack2_bf16(f2.z, f2.w),
                         pack2_bf16(f3.x, f3.y), pack2_bf16(f3.z, f3.w));
      } else {
        aw0 = make_uint4(0, 0, 0, 0); aw1 = make_uint4(0, 0, 0, 0);
      }
    } else {
      if (amok) {
        const uint4* pa = (const uint4*)(Ab + (size_t)arow * DMODEL + k0 + skc);
        aw0 = pa[0]; aw1 = pa[1];
      } else {
        aw0 = make_uint4(0, 0, 0, 0); aw1 = make_uint4(0, 0, 0, 0);
      }
    }
    const uint4* pw = (const uint4*)(Wb + (size_t)wrow * DMODEL + k0 + skc);
    uint4 ww0 = pw[0], ww1 = pw[1];
    *(uint4*)&As[srow * 40 + skc]     = aw0;
    *(uint4*)&As[srow * 40 + skc + 8] = aw1;
    *(uint4*)&Bs[srow * 40 + skc]     = ww0;
    *(uint4*)&Bs[srow * 40 + skc + 8] = ww1;
    __syncthreads();
    short8 a[4], b[4];
#pragma unroll
    for (int i = 0; i < 4; ++i)
      a[i] = *(const short8*)&As[(wm + i * 16 + m16) * 40 + quad * 8];
#pragma unroll
    for (int j = 0; j < 4; ++j)
      b[j] = *(const short8*)&Bs[(wn + j * 16 + m16) * 40 + quad * 8];
#pragma unroll
    for (int i = 0; i < 4; ++i)
#pragma unroll
      for (int j = 0; j < 4; ++j)
        acc[i][j] = __builtin_amdgcn_mfma_f32_16x16x32_bf16(a[i], b[j], acc[i][j], 0, 0, 0);
    __syncthreads();
  }

  // epilogue: C/D layout col=lane&15, row=quad*4+r (m89/m91)
  float bv[4]; int bcol[4];
#pragma unroll
  for (int j = 0; j < 4; ++j) {
    bcol[j] = bn + wn + j * 16 + m16;
    bv[j] = bias[bcol[j]];
  }
#pragma unroll
  for (int i = 0; i < 4; ++i) {
    const int rbase = bm + wm + i * 16 + quad * 4;
#pragma unroll
    for (int r = 0; r < 4; ++r) {
      const int row = rbase + r;
      if (row < M) {
#pragma unroll
        for (int j = 0; j < 4; ++j)
          C[(size_t)row * DMODEL + bcol[j]] = acc[i][j][r] + bv[j];
      }
    }
  }
}

// one block: prefix-scan query_mask -> left/right/nvalid per feature,
// plus compact list of fully-masked features (nvalid==0).
__global__ __launch_bounds__(1024) void build_segments(const int* __restrict__ qm,
    const int* __restrict__ ids, const int* __restrict__ padp,
    int n, int f, int* __restrict__ left, int* __restrict__ right,
    int* __restrict__ nvalid, int* __restrict__ fullrank,
    int* __restrict__ fullist, int* __restrict__ nfull) {
  __shared__ int cnt[1024];
  __shared__ int fullcnt;
  const int t = threadIdx.x;
  if (t == 0) fullcnt = 0;
  const int per = (n + 1023) >> 10;
  const int base = t * per;
  int c = 0;
  for (int i = 0; i < per; ++i) {
    int p = base + i;
    if (p < n && qm[p] != 0) ++c;
  }
  cnt[t] = c;
  __syncthreads();
  for (int off = 1; off < 1024; off <<= 1) {
    int v = (t >= off) ? cnt[t - off] : 0;
    __syncthreads();
    cnt[t] += v;
    __syncthreads();
  }
  int r = cnt[t] - c;  // exclusive prefix
  for (int i = 0; i < per; ++i) {
    int p = base + i;
    if (p < n && qm[p] != 0) {
      if (r < f) left[r] = p;
      ++r;
    }
  }
  __syncthreads();
  const int pad = *padp;
  for (int i = t; i < f; i += 1024) {
    int L0 = left[i];
    int R0 = (i + 1 < f) ? left[i + 1] : n;
    right[i] = R0;
    int cv = 0;
    for (int p = L0; p < R0; ++p) cv += (ids[p] != pad) ? 1 : 0;
    nvalid[i] = cv;
    if (cv == 0) {
      int rk = atomicAdd(&fullcnt, 1);
      if (rk < MAXFULL) { fullist[rk] = i; fullrank[i] = rk; }
      else fullrank[i] = -1;
    } else {
      fullrank[i] = -1;
    }
  }
  __syncthreads();
  if (t == 0) *nfull = (fullcnt < MAXFULL) ? fullcnt : MAXFULL;
}

__device__ __forceinline__ float allreduce64(float x) {
#pragma unroll
  for (int m = 1; m < 64; m <<= 1) x += __shfl_xor(x, m, 64);
  return x;
}

// normal features: online softmax over the (short) segment, skipping pad keys.
// Out-of-segment/pad contributions underflow to exact 0 in the reference's f32
// softmax, so segment-only is exact. Writes bf16 (input to the Wo GEMM).
__global__ __launch_bounds__(64) void attn_seg(const float* __restrict__ q,
    const float* __restrict__ k, const float* __restrict__ v,
    const int* __restrict__ left, const int* __restrict__ right,
    const int* __restrict__ nvalid, const int* __restrict__ ids,
    const int* __restrict__ padp, unsigned short* __restrict__ out) {
  const int feat = blockIdx.x, h = blockIdx.y, lane = threadIdx.x;
  if (nvalid[feat] == 0) return;  // handled by attn_full_*
  const int off = h * 64 + lane;
  const int pad = *padp;
  const float qv = q[(size_t)feat * DMODEL + off];
  float m = -1e30f, l = 0.f, acc = 0.f;
  const int L0 = left[feat], R0 = right[feat];
  for (int p = L0; p < R0; ++p) {
    if (ids[p] == pad) continue;
    float s = allreduce64(qv * k[(size_t)p * DMODEL + off]) * 0.125f;
    float mn = fmaxf(m, s);
    float al = __expf(m - mn);
    float w = __expf(s - mn);
    l = l * al + w;
    acc = acc * al + w * v[(size_t)p * DMODEL + off];
    m = mn;
  }
  out[(size_t)feat * DMODEL + off] = bf16_1(acc / l);
}

// fully-masked features: uniform -10000 bias cancels in softmax -> full softmax
// over ALL n keys (pads included, cross-batch). Split-K pass 1.
__global__ __launch_bounds__(512) void attn_full_part(const float* __restrict__ q,
    const float* __restrict__ k, const float* __restrict__ v,
    const int* __restrict__ fullist, const int* __restrict__ nfullp,
    int n, int split, float* __restrict__ pm, float* __restrict__ pl,
    float* __restrict__ pacc) {
  const int nfull = *nfullp;
  const int nitems = nfull * NHEADS * split;
  const int t = threadIdx.x, wave = t >> 6, lane = t & 63;
  __shared__ float sm[8], sl[8], sa[8][64];
  const int keys = n / split;
  for (int item = blockIdx.x; item < nitems; item += gridDim.x) {
    const int fl = item / (NHEADS * split);
    const int rem = item % (NHEADS * split);
    const int h = rem / split;
    const int sp = rem % split;
    const int feat = fullist[fl];
    const int off = h * 64 + lane;
    const float qv = q[(size_t)feat * DMODEL + off];
    const int p0 = sp * keys;
    float m = -1e30f, l = 0.f, acc = 0.f;
    for (int p = p0 + wave; p < p0 + keys; p += 8) {
      float s = allreduce64(qv * k[(size_t)p * DMODEL + off]) * 0.125f;
      float mn = fmaxf(m, s);
      float al = __expf(m - mn);
      float w = __expf(s - mn);
      l = l * al + w;
      acc = acc * al + w * v[(size_t)p * DMODEL + off];
      m = mn;
    }
    if (lane == 0) { sm[wave] = m; sl[wave] = l; }
    sa[wave][lane] = acc;
    __syncthreads();
    if (wave == 0) {
      float M = -1e30f;
#pragma unroll
      for (int w2 = 0; w2 < 8; ++w2) M = fmaxf(M, sm[w2]);
      float Lt = 0.f, At = 0.f;
#pragma unroll
      for (int w2 = 0; w2 < 8; ++w2) {
        float sc = __expf(sm[w2] - M);
        Lt += sl[w2] * sc;
        At += sa[w2][lane] * sc;
      }
      size_t idx = ((size_t)fl * NHEADS + h) * split + sp;
      if (lane == 0) { pm[idx] = M; pl[idx] = Lt; }
      pacc[idx * 64 + lane] = At;
    }
    __syncthreads();
  }
}

// Split-K pass 2: merge the partials per (feature, head). Writes bf16.
__global__ __launch_bounds__(64) void attn_full_comb(
    const int* __restrict__ nvalid, const int* __restrict__ fullrank,
    int split, const float* __restrict__ pm, const float* __restrict__ pl,
    const float* __restrict__ pacc, unsigned short* __restrict__ out) {
  const int feat = blockIdx.x, h = blockIdx.y, lane = threadIdx.x;
  if (nvalid[feat] != 0) return;
  const int fl = fullrank[feat];
  if (fl < 0) return;
  const size_t base = ((size_t)fl * NHEADS + h) * split;
  float M = -1e30f;
  for (int sp = 0; sp < split; ++sp) M = fmaxf(M, pm[base + sp]);
  float Lt = 0.f, At = 0.f;
  for (int sp = 0; sp < split; ++sp) {
    float sc = __expf(pm[base + sp] - M);
    Lt += pl[base + sp] * sc;
    At += pacc[(base + sp) * 64 + lane] * sc;
  }
  out[(size_t)feat * DMODEL + h * 64 + lane] = bf16_1(At / Lt);
}

extern "C" void kernel_launch(void* const* d_in, const int* in_sizes, int n_in,
                              void* d_out, int out_size, void* d_ws, size_t ws_size,
                              hipStream_t stream) {
  const float* x_qk = (const float*)d_in[0];
  const float* x_v  = (const float*)d_in[1];
  const int* qm     = (const int*)d_in[2];
  const int* ids    = (const int*)d_in[3];
  const int* padp   = (const int*)d_in[4];
  const float* Wq = (const float*)d_in[5];
  const float* bq = (const float*)d_in[6];
  const float* Wk = (const float*)d_in[7];
  const float* bk = (const float*)d_in[8];
  const float* Wv = (const float*)d_in[9];
  const float* bv = (const float*)d_in[10];
  const float* Wo = (const float*)d_in[11];
  const float* bo = (const float*)d_in[12];

  const int n = in_sizes[0] / DMODEL;   // 8192
  const int f = out_size / DMODEL;      // 1024

  // ws layout: kf,vf,qf f32 | af bf16 | Wbf x4 | ints | split partials
  float* kf = (float*)d_ws;
  float* vf = kf + (size_t)n * DMODEL;
  float* qf = vf + (size_t)n * DMODEL;
  unsigned short* af = (unsigned short*)(qf + (size_t)f * DMODEL);
  unsigned short* wqb = af + (size_t)f * DMODEL;
  unsigned short* wkb = wqb + DMODEL * DMODEL;
  unsigned short* wvb = wkb + DMODEL * DMODEL;
  unsigned short* wob = wvb + DMODEL * DMODEL;
  int* left     = (int*)(wob + DMODEL * DMODEL);
  int* right    = left + f;
  int* nvalid   = right + f;
  int* fullrank = nvalid + f;
  int* fullist  = fullrank + f;
  int* nfull    = fullist + MAXFULL;
  size_t off_bytes = ((size_t)((char*)(nfull + 1) - (char*)d_ws) + 255) & ~(size_t)255;
  int split = 64;
  while (split > 8) {
    size_t need = (size_t)MAXFULL * NHEADS * split * 66 * sizeof(float);
    if (off_bytes + need <= ws_size) break;
    split >>= 1;
  }
  float* pm = (float*)((char*)d_ws + off_bytes);
  float* pl = pm + (size_t)MAXFULL * NHEADS * split;
  float* pacc = pl + (size_t)MAXFULL * NHEADS * split;

  build_segments<<<1, 1024, 0, stream>>>(qm, ids, padp, n, f, left, right,
                                         nvalid, fullrank, fullist, nfull);
  convW<<<1152, 256, 0, stream>>>(Wq, Wk, Wv, Wo, (unsigned*)wqb, (unsigned*)wkb,
                                  (unsigned*)wvb, (unsigned*)wob, DMODEL * DMODEL);

  dim3 gKV(6, (n + 127) / 128);
  dim3 gF(6, (f + 127) / 128);
  gemm_mfma<1><<<gKV, 256, 0, stream>>>(x_qk, wkb, bk, nullptr, kf, n);
  gemm_mfma<1><<<gKV, 256, 0, stream>>>(x_v,  wvb, bv, nullptr, vf, n);
  gemm_mfma<1><<<gF,  256, 0, stream>>>(x_qk, wqb, bq, left,    qf, f);

  attn_seg<<<dim3(f, NHEADS), 64, 0, stream>>>(qf, kf, vf, left, right, nvalid,
                                               ids, padp, af);
  attn_full_part<<<3072, 512, 0, stream>>>(qf, kf, vf, fullist, nfull, n, split,
                                           pm, pl, pacc);
  attn_full_comb<<<dim3(f, NHEADS), 64, 0, stream>>>(nvalid, fullrank, split,
                                                     pm, pl, pacc, af);

  gemm_mfma<0><<<gF, 256, 0, stream>>>(af, wob, bo, nullptr, (float*)d_out, f);
}